// Round 22
// baseline (656.052 us; speedup 1.0000x reference)
//
#include <hip/hip_runtime.h>
#include <math.h>

#define NN 576
#define LAMC 0.1f
#define NUM_STEP 10

typedef unsigned short u16;
typedef __attribute__((ext_vector_type(8))) short bf16x8;
typedef __attribute__((ext_vector_type(4))) float f32x4;

__device__ __forceinline__ float bf2f(u16 u) { return __uint_as_float(((unsigned)u) << 16); }
__device__ __forceinline__ u16 f2bf(float f) {
    unsigned x = __float_as_uint(f);
    return (u16)((x + 0x7fffu + ((x >> 16) & 1u)) >> 16);
}
__device__ __forceinline__ float soft_thresh(float z, float t) {
    float a = fabsf(z) - t;
    float g = 0.5f * a * (1.0f + erff(a * 0.70710678118654752f));
    float s = (z > 0.0f) ? 1.0f : ((z < 0.0f) ? -1.0f : 0.0f);
    return s * g;
}
// async global->LDS, 16B per lane: lds dest = uniform base + lane*16
__device__ __forceinline__ void gload16(const u16* g, const u16* l) {
    __builtin_amdgcn_global_load_lds(
        (const __attribute__((address_space(1))) unsigned int*)(g),
        (__attribute__((address_space(3))) unsigned int*)(l), 16, 0, 0);
}

// ---------- K0: merged preps ----------
__global__ __launch_bounds__(256) void k_prep(const float* __restrict__ x,
                                              const float* __restrict__ qkv_w,
                                              const float* __restrict__ proj_w,
                                              const float* __restrict__ Lk,
                                              const float* __restrict__ rand_m,
                                              const float* __restrict__ kern,
                                              u16* __restrict__ xb,
                                              u16* __restrict__ wb,
                                              u16* __restrict__ pwb,
                                              u16* __restrict__ Lkb,
                                              u16* __restrict__ LkTb,
                                              u16* __restrict__ randT,
                                              u16* __restrict__ kerT) {
    const int b = blockIdx.x;
    if (b < 18432) {
        const int i = b * 256 + threadIdx.x;
        float4 v = reinterpret_cast<const float4*>(x)[i];
        ushort4 o; o.x = f2bf(v.x); o.y = f2bf(v.y); o.z = f2bf(v.z); o.w = f2bf(v.w);
        reinterpret_cast<ushort4*>(xb)[i] = o;
    } else if (b < 20480) {
        const int i = (b - 18432) * 256 + threadIdx.x;
        float4 v = reinterpret_cast<const float4*>(qkv_w)[i];
        ushort4 o; o.x = f2bf(v.x); o.y = f2bf(v.y); o.z = f2bf(v.z); o.w = f2bf(v.w);
        reinterpret_cast<ushort4*>(wb)[i] = o;
    } else if (b < 21504) {
        const int i = (b - 20480) * 256 + threadIdx.x;
        float4 v = reinterpret_cast<const float4*>(proj_w)[i];
        ushort4 o; o.x = f2bf(v.x); o.y = f2bf(v.y); o.z = f2bf(v.z); o.w = f2bf(v.w);
        reinterpret_cast<ushort4*>(pwb)[i] = o;
    } else if (b < 21568) {
        const int i = (b - 21504) * 256 + threadIdx.x;
        float4 v = reinterpret_cast<const float4*>(Lk)[i];
        ushort4 o; o.x = f2bf(v.x); o.y = f2bf(v.y); o.z = f2bf(v.z); o.w = f2bf(v.w);
        reinterpret_cast<ushort4*>(Lkb)[i] = o;
    } else if (b < 21824) {
        const int r = b - 21568, s = threadIdx.x;
        LkTb[r * 256 + s] = f2bf(Lk[s * 256 + r]);
    } else if (b < 22336) {
        const int i = (b - 21824) * 256 + threadIdx.x;
        const int h = i >> 13, rem = i & 8191;
        const int m = rem >> 6, d = rem & 63;
        randT[i] = f2bf(rand_m[(size_t)h * 8192 + d * 128 + m]);
    } else {
        const int h = b - 22336, m = threadIdx.x;
        if (m < 128) {
            const float* kp = kern + (size_t)h * NN * 128 + m;
            float s = 0.f;
            for (int n = 0; n < NN; ++n) { float v = kp[(size_t)n * 128]; s = fmaf(v, v, s); }
            const float inv = 1.0f / fmaxf(sqrtf(s), 1e-12f);
            u16* op = kerT + ((size_t)h * 128 + m) * 576;
            for (int n = 0; n < NN; ++n) op[n] = f2bf(kp[(size_t)n * 128] * inv);
        }
    }
}

// ---------- shared NT-MFMA 128x128 core, BK=64, slot-swizzled ----------
__device__ __forceinline__ void nt128_k64(const u16* __restrict__ A, const u16* __restrict__ B,
                                          const int K, u16 (&As)[128][64], u16 (&Bs)[128][64],
                                          f32x4 (&acc)[4][4]) {
    const int tid = threadIdx.x;
    const int lane = tid & 63, wid = tid >> 6;
    const int wr = (wid >> 1) * 64, wc = (wid & 1) * 64;
    const int fr = lane & 15, kg = lane >> 4;
    const int lrow = lane >> 3;
    const int lslot = (lane & 7) ^ ((lane >> 3) & 7);
    for (int k0 = 0; k0 < K; k0 += 64) {
        __syncthreads();
        #pragma unroll
        for (int c = 0; c < 4; ++c) {
            const int ch = wid + c * 4;
            gload16(&A[(size_t)(ch * 8 + lrow) * K + k0 + lslot * 8], &As[ch * 8][0]);
            gload16(&B[(size_t)(ch * 8 + lrow) * K + k0 + lslot * 8], &Bs[ch * 8][0]);
        }
        __syncthreads();
        #pragma unroll
        for (int ks = 0; ks < 2; ++ks) {
            const int rs = ((ks * 4 + kg) ^ (fr & 7)) * 8;
            bf16x8 af[4], bfr[4];
            #pragma unroll
            for (int i = 0; i < 4; ++i) af[i] = *reinterpret_cast<const bf16x8*>(&As[wr + i * 16 + fr][rs]);
            #pragma unroll
            for (int j = 0; j < 4; ++j) bfr[j] = *reinterpret_cast<const bf16x8*>(&Bs[wc + j * 16 + fr][rs]);
            #pragma unroll
            for (int i = 0; i < 4; ++i)
                #pragma unroll
                for (int j = 0; j < 4; ++j)
                    acc[i][j] = __builtin_amdgcn_mfma_f32_16x16x32_bf16(af[i], bfr[j], acc[i][j], 0, 0, 0);
        }
    }
}

// ---------- K1: qkv GEMM (128x128, BK=64) -> qbf / vT ----------
__global__ __launch_bounds__(256, 4) void k_qkv_mfma(const u16* __restrict__ A,
                                                     const u16* __restrict__ B,
                                                     u16* __restrict__ qbf,
                                                     u16* __restrict__ vT) {
    __shared__ u16 As[128][64];
    __shared__ u16 Bs[128][64];
    const int tid = threadIdx.x;
    const int wid = tid >> 6, lane = tid & 63;
    const int wr = (wid >> 1) * 64, wc = (wid & 1) * 64;
    const int lb = (blockIdx.x & 7) * 288 + (blockIdx.x >> 3);
    const int bm = lb >> 4, bn = lb & 15;
    const int row0 = bm * 128, col0 = bn * 128;
    const int fr = lane & 15, kg = lane >> 4;
    f32x4 acc[4][4];
    #pragma unroll
    for (int i = 0; i < 4; ++i)
        #pragma unroll
        for (int j = 0; j < 4; ++j) acc[i][j] = (f32x4){0.f, 0.f, 0.f, 0.f};
    nt128_k64(A + (size_t)row0 * 1024, B + (size_t)col0 * 1024, 1024, As, Bs, acc);
    const bool isQ = (col0 < 1024);
    if (isQ) {
        const float qscale = 0.35355339059327373f;
        #pragma unroll
        for (int i = 0; i < 4; ++i) {
            #pragma unroll
            for (int r = 0; r < 4; ++r) {
                const int grow = row0 + wr + i * 16 + kg * 4 + r;
                const int b = grow / NN, n = grow % NN;
                #pragma unroll
                for (int j = 0; j < 4; ++j) {
                    const int gcol = col0 + wc + j * 16 + fr;
                    const int h = gcol >> 6, d = gcol & 63;
                    qbf[(((size_t)b * 16 + h) * NN + n) * 64 + d] = f2bf(acc[i][j][r] * qscale);
                }
            }
        }
    } else {
        #pragma unroll
        for (int i = 0; i < 4; ++i) {
            const int gb = row0 + wr + i * 16 + kg * 4;
            const int b = gb / NN, n = gb % NN;
            #pragma unroll
            for (int j = 0; j < 4; ++j) {
                const int c2 = col0 + wc + j * 16 + fr - 1024;
                const int h = c2 >> 6, d = c2 & 63;
                ushort4 pk;
                pk.x = f2bf(acc[i][j][0]); pk.y = f2bf(acc[i][j][1]);
                pk.z = f2bf(acc[i][j][2]); pk.w = f2bf(acc[i][j][3]);
                *reinterpret_cast<ushort4*>(&vT[(((size_t)b * 16 + h) * 64 + d) * 576 + n]) = pk;
            }
        }
    }
}

// ---------- K2: performer phi via MFMA -> phiT (UNSCALED) + invn ----------
__global__ __launch_bounds__(256) void k_phi_mfma(const u16* __restrict__ qbf,
                                                  const u16* __restrict__ randT,
                                                  u16* __restrict__ phiT,
                                                  float* __restrict__ invn) {
    __shared__ u16 Rs[128][72];
    __shared__ u16 Qs[64][72];
    __shared__ u16 Ph[128][72];
    __shared__ float sn[64];
    __shared__ float snorm[256];
    const int bh = blockIdx.x, h = bh & 15;
    const int tid = threadIdx.x, lane = tid & 63, wid = tid >> 6;
    const int fr = lane & 15, kg = lane >> 4;
    #pragma unroll
    for (int c = 0; c < 4; ++c) {
        const int i = c * 256 + tid;
        const int m = i >> 3, k8 = (i & 7) * 8;
        *reinterpret_cast<uint4*>(&Rs[m][k8]) =
            *reinterpret_cast<const uint4*>(&randT[((size_t)h * 128 + m) * 64 + k8]);
    }
    const u16* Q = qbf + (size_t)bh * 576 * 64;
    const float invM = 0.08838834764831845f;
    float accs = 0.f;
    const int m2 = tid >> 1, c0 = (tid & 1) * 32;
    for (int nc = 0; nc < 9; ++nc) {
        const int n0 = nc * 64;
        __syncthreads();
        #pragma unroll
        for (int c = 0; c < 2; ++c) {
            const int i = c * 256 + tid;
            const int r = i >> 3, k8 = (i & 7) * 8;
            *reinterpret_cast<uint4*>(&Qs[r][k8]) =
                *reinterpret_cast<const uint4*>(&Q[(size_t)(n0 + r) * 64 + k8]);
        }
        __syncthreads();
        if (tid < 64) {
            float s = 0.f;
            #pragma unroll 8
            for (int d = 0; d < 64; ++d) { float v = bf2f(Qs[tid][d]); s = fmaf(v, v, s); }
            sn[tid] = 0.5f * s;
        }
        f32x4 acc[2][4];
        #pragma unroll
        for (int i = 0; i < 2; ++i)
            #pragma unroll
            for (int j = 0; j < 4; ++j) acc[i][j] = (f32x4){0.f, 0.f, 0.f, 0.f};
        #pragma unroll
        for (int ks = 0; ks < 2; ++ks) {
            bf16x8 af[2], bq[4];
            #pragma unroll
            for (int i = 0; i < 2; ++i)
                af[i] = *reinterpret_cast<const bf16x8*>(&Rs[wid * 32 + i * 16 + fr][ks * 32 + kg * 8]);
            #pragma unroll
            for (int j = 0; j < 4; ++j)
                bq[j] = *reinterpret_cast<const bf16x8*>(&Qs[j * 16 + fr][ks * 32 + kg * 8]);
            #pragma unroll
            for (int i = 0; i < 2; ++i)
                #pragma unroll
                for (int j = 0; j < 4; ++j)
                    acc[i][j] = __builtin_amdgcn_mfma_f32_16x16x32_bf16(af[i], bq[j], acc[i][j], 0, 0, 0);
        }
        __syncthreads();
        #pragma unroll
        for (int j = 0; j < 4; ++j) {
            const int n = j * 16 + fr;
            const float sv = sn[n];
            #pragma unroll
            for (int i = 0; i < 2; ++i) {
                #pragma unroll
                for (int r = 0; r < 4; ++r) {
                    const int m = wid * 32 + i * 16 + kg * 4 + r;
                    Ph[m][n] = f2bf(expf(acc[i][j][r] - sv) * invM);
                }
            }
        }
        __syncthreads();
        #pragma unroll
        for (int c = 0; c < 4; ++c) {
            const int i = c * 256 + tid;
            const int mm = i >> 3, k8 = (i & 7) * 8;
            *reinterpret_cast<uint4*>(&phiT[((size_t)bh * 128 + mm) * 576 + n0 + k8]) =
                *reinterpret_cast<const uint4*>(&Ph[mm][k8]);
        }
        {
            float s = 0.f;
            #pragma unroll 8
            for (int t = 0; t < 32; ++t) { float v = bf2f(Ph[m2][c0 + t]); s = fmaf(v, v, s); }
            accs += s;
        }
    }
    snorm[tid] = accs;
    __syncthreads();
    if (tid < 128)
        invn[bh * 128 + tid] = 1.0f / fmaxf(sqrtf(snorm[tid * 2] + snorm[tid * 2 + 1]), 1e-12f);
}

// ---------- K5: gram FAT (BK=64) + fused eff_L ----------
__global__ __launch_bounds__(512, 2) void k_gram_fat(const u16* __restrict__ phiT,
                                                     const u16* __restrict__ kerT,
                                                     const float* __restrict__ invn,
                                                     const float* __restrict__ lL,
                                                     u16* __restrict__ kkb,
                                                     float* __restrict__ effL) {
    __shared__ u16 Qs[256][64];
    __shared__ float rs2[2][256];
    __shared__ float red[256];
    const int bh = blockIdx.x, h = bh & 15;
    const int tid = threadIdx.x, lane = tid & 63, wid = tid >> 6;
    const int wr = (wid & 3) * 64, wc = (wid >> 2) * 128;
    const int fr = lane & 15, kg = lane >> 4;
    const int lrow = lane >> 3;
    const int lslot = (lane & 7) ^ ((lane >> 3) & 7);
    f32x4 acc[4][8];
    #pragma unroll
    for (int i = 0; i < 4; ++i)
        #pragma unroll
        for (int j = 0; j < 8; ++j) acc[i][j] = (f32x4){0.f, 0.f, 0.f, 0.f};
    for (int k0 = 0; k0 < 576; k0 += 64) {
        __syncthreads();
        #pragma unroll
        for (int c = 0; c < 4; ++c) {
            const int rowbase = (wid * 4 + c) * 8;
            const int p = rowbase + lrow;
            const u16* src = (p < 128)
                ? phiT + ((size_t)bh * 128 + p) * 576 + k0 + lslot * 8
                : kerT + ((size_t)h * 128 + (p - 128)) * 576 + k0 + lslot * 8;
            gload16(src, &Qs[rowbase][0]);
        }
        __syncthreads();
        #pragma unroll
        for (int ks = 0; ks < 2; ++ks) {
            const int rs = ((ks * 4 + kg) ^ (fr & 7)) * 8;
            bf16x8 af[4], bf[8];
            #pragma unroll
            for (int i = 0; i < 4; ++i) af[i] = *reinterpret_cast<const bf16x8*>(&Qs[wr + i * 16 + fr][rs]);
            #pragma unroll
            for (int j = 0; j < 8; ++j) bf[j] = *reinterpret_cast<const bf16x8*>(&Qs[wc + j * 16 + fr][rs]);
            #pragma unroll
            for (int i = 0; i < 4; ++i)
                #pragma unroll
                for (int j = 0; j < 8; ++j)
                    acc[i][j] = __builtin_amdgcn_mfma_f32_16x16x32_bf16(af[i], bf[j], acc[i][j], 0, 0, 0);
        }
    }
    const float* iv = invn + bh * 128;
    u16* C = kkb + (size_t)bh * 65536;
    float sq[8];
    #pragma unroll
    for (int j = 0; j < 8; ++j) { const int q = wc + j * 16 + fr; sq[j] = (q < 128) ? iv[q] : 1.0f; }
    #pragma unroll
    for (int i = 0; i < 4; ++i)
        #pragma unroll
        for (int rr = 0; rr < 4; ++rr) {
            const int p = wr + i * 16 + kg * 4 + rr;
            const float sp = (p < 128) ? iv[p] : 1.0f;
            float rsum = 0.f;
            #pragma unroll
            for (int j = 0; j < 8; ++j) {
                const float val = acc[i][j][rr] * sp * sq[j];
                C[(size_t)p * 256 + wc + j * 16 + fr] = f2bf(val);
                rsum += fabsf(val);
            }
            #pragma unroll
            for (int mk = 1; mk < 16; mk <<= 1) rsum += __shfl_xor(rsum, mk);
            if (fr == 0) rs2[wid >> 2][p] = rsum;
        }
    __syncthreads();
    if (tid < 256) red[tid] = rs2[0][tid] + rs2[1][tid];
    __syncthreads();
    for (int st = 128; st > 0; st >>= 1) {
        if (tid < st) red[tid] = fmaxf(red[tid], red[tid + st]);
        __syncthreads();
    }
    if (tid == 0) effL[bh] = (red[0] + 1.0f) / lL[0];
}

// ---------- K6: fused Lk sandwich: kk = Lk·kk·Lk in ONE kernel (t in LDS) ----------
__global__ __launch_bounds__(512, 1) void k_lk_fused(const u16* __restrict__ Lkb,
                                                     const u16* __restrict__ LkTb,
                                                     u16* __restrict__ kkb) {
    __shared__ u16 smem[73728];                                    // 147456 B
    u16 (*t)[256]  = reinterpret_cast<u16(*)[256]>(smem);
    u16 (*As1)[64] = reinterpret_cast<u16(*)[64]>(smem);
    u16 (*Bs1)[64] = reinterpret_cast<u16(*)[64]>(smem + 16384);
    u16 (*Bs2)[32] = reinterpret_cast<u16(*)[32]>(smem + 65536);
    const int bh = blockIdx.x;
    const int tid = threadIdx.x, lane = tid & 63, wid = tid >> 6;
    const int wr = (wid & 3) * 64, wc = (wid >> 2) * 128;
    const int fr = lane & 15, kg = lane >> 4;
    const u16* B1 = kkb + (size_t)bh * 65536;
    f32x4 acc[4][8];
    #pragma unroll
    for (int i = 0; i < 4; ++i)
        #pragma unroll
        for (int j = 0; j < 8; ++j) acc[i][j] = (f32x4){0.f, 0.f, 0.f, 0.f};
    {
        const int lrow = lane >> 3;
        const int lslot = (lane & 7) ^ ((lane >> 3) & 7);
        for (int k0 = 0; k0 < 256; k0 += 64) {
            __syncthreads();
            #pragma unroll
            for (int c = 0; c < 4; ++c) {
                const int rowbase = (wid * 4 + c) * 8;
                const int p = rowbase + lrow;
                gload16(&Lkb[(size_t)p * 256 + k0 + lslot * 8], &As1[rowbase][0]);
                gload16(&B1[(size_t)p * 256 + k0 + lslot * 8], &Bs1[rowbase][0]);
            }
            __syncthreads();
            #pragma unroll
            for (int ks = 0; ks < 2; ++ks) {
                const int rs = ((ks * 4 + kg) ^ (fr & 7)) * 8;
                bf16x8 af[4], bf[8];
                #pragma unroll
                for (int i = 0; i < 4; ++i) af[i] = *reinterpret_cast<const bf16x8*>(&As1[wr + i * 16 + fr][rs]);
                #pragma unroll
                for (int j = 0; j < 8; ++j) bf[j] = *reinterpret_cast<const bf16x8*>(&Bs1[wc + j * 16 + fr][rs]);
                #pragma unroll
                for (int i = 0; i < 4; ++i)
                    #pragma unroll
                    for (int j = 0; j < 8; ++j)
                        acc[i][j] = __builtin_amdgcn_mfma_f32_16x16x32_bf16(af[i], bf[j], acc[i][j], 0, 0, 0);
            }
        }
    }
    __syncthreads();
    #pragma unroll
    for (int i = 0; i < 4; ++i)
        #pragma unroll
        for (int rr = 0; rr < 4; ++rr) {
            const int p = wr + i * 16 + kg * 4 + rr;
            #pragma unroll
            for (int j = 0; j < 8; ++j) {
                const int q = wc + j * 16 + fr;
                t[p][q ^ ((p & 7) << 3)] = f2bf(acc[i][j][rr]);
            }
        }
    __syncthreads();
    #pragma unroll
    for (int i = 0; i < 4; ++i)
        #pragma unroll
        for (int j = 0; j < 8; ++j) acc[i][j] = (f32x4){0.f, 0.f, 0.f, 0.f};
    {
        const int lrow2 = lane >> 2;
        const int lslot2 = (lane & 3) ^ ((lane >> 3) & 3);
        const int rslot2 = (kg ^ ((fr >> 1) & 3)) * 8;
        for (int k0 = 0; k0 < 256; k0 += 32) {
            __syncthreads();
            #pragma unroll
            for (int c = 0; c < 2; ++c) {
                const int chunk = wid * 2 + c;
                const int p = chunk * 16 + lrow2;
                gload16(&LkTb[(size_t)p * 256 + k0 + lslot2 * 8], &Bs2[chunk * 16][0]);
            }
            __syncthreads();
            bf16x8 af[4], bf[8];
            #pragma unroll
            for (int i = 0; i < 4; ++i) {
                const int p = wr + i * 16 + fr;
                af[i] = *reinterpret_cast<const bf16x8*>(&t[p][(k0 + kg * 8) ^ ((p & 7) << 3)]);
            }
            #pragma unroll
            for (int j = 0; j < 8; ++j) bf[j] = *reinterpret_cast<const bf16x8*>(&Bs2[wc + j * 16 + fr][rslot2]);
            #pragma unroll
            for (int i = 0; i < 4; ++i)
                #pragma unroll
                for (int j = 0; j < 8; ++j)
                    acc[i][j] = __builtin_amdgcn_mfma_f32_16x16x32_bf16(af[i], bf[j], acc[i][j], 0, 0, 0);
        }
    }
    u16* C = kkb + (size_t)bh * 65536;
    #pragma unroll
    for (int i = 0; i < 4; ++i)
        #pragma unroll
        for (int rr = 0; rr < 4; ++rr) {
            const int p = wr + i * 16 + kg * 4 + rr;
            #pragma unroll
            for (int j = 0; j < 8; ++j)
                C[(size_t)p * 256 + wc + j * 16 + fr] = f2bf(acc[i][j][rr]);
        }
}

// ---------- K7: inp (MFMA, BK=64, async-staged, invn folded at store) ----------
__global__ __launch_bounds__(256, 4) void k_inp_mfma(const u16* __restrict__ vT,
                                                     const u16* __restrict__ phiT,
                                                     const u16* __restrict__ kerT,
                                                     const float* __restrict__ invn,
                                                     float* __restrict__ inpT) {
    __shared__ u16 As[64][64];
    __shared__ u16 Bs[256][64];
    const int bh = blockIdx.x, h = bh & 15;
    const int tid = threadIdx.x, lane = tid & 63, wid = tid >> 6;
    const int fr = lane & 15, kg = lane >> 4;
    const int lrow = lane >> 3;
    const int lslot = (lane & 7) ^ ((lane >> 3) & 7);
    const u16* Av = vT + (size_t)bh * 64 * 576;
    f32x4 acc[4][4];
    #pragma unroll
    for (int i = 0; i < 4; ++i)
        #pragma unroll
        for (int j = 0; j < 4; ++j) acc[i][j] = (f32x4){0.f, 0.f, 0.f, 0.f};
    for (int k0 = 0; k0 < 576; k0 += 64) {
        __syncthreads();
        #pragma unroll
        for (int c = 0; c < 2; ++c) {
            const int chunk = wid * 2 + c;
            gload16(&Av[(size_t)(chunk * 8 + lrow) * 576 + k0 + lslot * 8], &As[chunk * 8][0]);
        }
        #pragma unroll
        for (int c = 0; c < 8; ++c) {
            const int chunk = wid + c * 4;
            const int p = chunk * 8 + lrow;
            const u16* src = (p < 128)
                ? phiT + ((size_t)bh * 128 + p) * 576 + k0 + lslot * 8
                : kerT + ((size_t)h * 128 + (p - 128)) * 576 + k0 + lslot * 8;
            gload16(src, &Bs[chunk * 8][0]);
        }
        __syncthreads();
        #pragma unroll
        for (int ks = 0; ks < 2; ++ks) {
            const int rs = ((ks * 4 + kg) ^ (fr & 7)) * 8;
            bf16x8 af[4], bfr[4];
            #pragma unroll
            for (int i = 0; i < 4; ++i) af[i] = *reinterpret_cast<const bf16x8*>(&As[i * 16 + fr][rs]);
            #pragma unroll
            for (int j = 0; j < 4; ++j) bfr[j] = *reinterpret_cast<const bf16x8*>(&Bs[wid * 64 + j * 16 + fr][rs]);
            #pragma unroll
            for (int i = 0; i < 4; ++i)
                #pragma unroll
                for (int j = 0; j < 4; ++j)
                    acc[i][j] = __builtin_amdgcn_mfma_f32_16x16x32_bf16(af[i], bfr[j], acc[i][j], 0, 0, 0);
        }
    }
    float* O = inpT + (size_t)bh * 16384;
    float sc[4];
    #pragma unroll
    for (int j = 0; j < 4; ++j) {
        const int p = wid * 64 + j * 16 + fr;
        sc[j] = (p < 128) ? invn[bh * 128 + p] : 1.0f;
    }
    #pragma unroll
    for (int i = 0; i < 4; ++i)
        #pragma unroll
        for (int r = 0; r < 4; ++r)
            #pragma unroll
            for (int j = 0; j < 4; ++j)
                O[(size_t)(i * 16 + kg * 4 + r) * 256 + wid * 64 + j * 16 + fr] = acc[i][j][r] * sc[j];
}

// ---------- K10: fused ISTA, double-buffered z, XCD-paired, occupancy hint ----------
__global__ __launch_bounds__(256, 4) void k_ista_reg(const u16* __restrict__ kkl,
                                                     const float* __restrict__ inpT,
                                                     u16* __restrict__ zbf,
                                                     const float* __restrict__ effL,
                                                     const float* __restrict__ llam) {
    __shared__ u16 zs[2][32][256];
    const int lb = (blockIdx.x & 7) * 128 + (blockIdx.x >> 3);
    const int bh = lb >> 1, dh = lb & 1;
    const int tid = threadIdx.x, lane = tid & 63, wid = tid >> 6;
    const int wr = wid * 64;
    const int fr = lane & 15, kg = lane >> 4;
    const u16* Kk = kkl + (size_t)bh * 65536;
    bf16x8 af[4][8];
    #pragma unroll
    for (int i = 0; i < 4; ++i) {
        const int p = wr + i * 16 + fr;
        #pragma unroll
        for (int c = 0; c < 8; ++c)
            af[i][c] = *reinterpret_cast<const bf16x8*>(&Kk[(size_t)p * 256 + c * 32 + kg * 8]);
    }
    const float* I = inpT + (size_t)bh * 16384 + (size_t)dh * 32 * 256;
    const float invL = 1.0f / effL[bh];
    const float lam = llam[0] * LAMC;
    const float thr = lam * invL;
    float4 ip[4][2];
    #pragma unroll
    for (int i = 0; i < 4; ++i) {
        const int pb = wr + i * 16 + kg * 4;
        #pragma unroll
        for (int j = 0; j < 2; ++j) {
            const int d = j * 16 + fr;
            ip[i][j] = *reinterpret_cast<const float4*>(&I[(size_t)d * 256 + pb]);
            const int pc = pb ^ ((d & 7) << 3);
            ushort4 pk;
            pk.x = f2bf(soft_thresh(ip[i][j].x, lam));
            pk.y = f2bf(soft_thresh(ip[i][j].y, lam));
            pk.z = f2bf(soft_thresh(ip[i][j].z, lam));
            pk.w = f2bf(soft_thresh(ip[i][j].w, lam));
            *reinterpret_cast<ushort4*>(&zs[0][d][pc]) = pk;
        }
    }
    __syncthreads();
    int cur = 0;
    for (int step = 0; step < NUM_STEP; ++step) {
        f32x4 acc[4][2];
        #pragma unroll
        for (int i = 0; i < 4; ++i)
            #pragma unroll
            for (int j = 0; j < 2; ++j) acc[i][j] = (f32x4){0.f, 0.f, 0.f, 0.f};
        #pragma unroll
        for (int c = 0; c < 8; ++c) {
            bf16x8 bz[2];
            #pragma unroll
            for (int j = 0; j < 2; ++j) {
                const int d = j * 16 + fr;
                bz[j] = *reinterpret_cast<const bf16x8*>(&zs[cur][d][(c * 32 + kg * 8) ^ ((d & 7) << 3)]);
            }
            #pragma unroll
            for (int i = 0; i < 4; ++i)
                #pragma unroll
                for (int j = 0; j < 2; ++j)
                    acc[i][j] = __builtin_amdgcn_mfma_f32_16x16x32_bf16(af[i][c], bz[j], acc[i][j], 0, 0, 0);
        }
        #pragma unroll
        for (int i = 0; i < 4; ++i) {
            const int pb = wr + i * 16 + kg * 4;
            #pragma unroll
            for (int j = 0; j < 2; ++j) {
                const int d = j * 16 + fr;
                const int pc = pb ^ ((d & 7) << 3);
                ushort4 zo = *reinterpret_cast<const ushort4*>(&zs[cur][d][pc]);
                ushort4 pk;
                pk.x = f2bf(soft_thresh(bf2f(zo.x) - (acc[i][j][0] - ip[i][j].x) * invL, thr));
                pk.y = f2bf(soft_thresh(bf2f(zo.y) - (acc[i][j][1] - ip[i][j].y) * invL, thr));
                pk.z = f2bf(soft_thresh(bf2f(zo.z) - (acc[i][j][2] - ip[i][j].z) * invL, thr));
                pk.w = f2bf(soft_thresh(bf2f(zo.w) - (acc[i][j][3] - ip[i][j].w) * invL, thr));
                *reinterpret_cast<ushort4*>(&zs[cur ^ 1][d][pc]) = pk;
            }
        }
        __syncthreads();
        cur ^= 1;
    }
    u16* Z = zbf + (size_t)bh * 16384 + (size_t)dh * 32 * 256;
    #pragma unroll
    for (int c = 0; c < 4; ++c) {
        const int i = c * 256 + tid;
        const int d = i >> 5, p8 = (i & 31) * 8;
        *reinterpret_cast<uint4*>(&Z[(size_t)d * 256 + p8]) =
            *reinterpret_cast<const uint4*>(&zs[0][d][p8 ^ ((d & 7) << 3)]);
    }
}

// ---------- K11: out_pre via MFMA (invn folded into Zs staging) ----------
__global__ __launch_bounds__(256) void k_outpre_mfma(const u16* __restrict__ phiT,
                                                     const u16* __restrict__ kerT,
                                                     const u16* __restrict__ zbf,
                                                     const float* __restrict__ invn,
                                                     u16* __restrict__ outp) {
    __shared__ u16 Zs[64][264];
    __shared__ u16 Qt[64][264];
    __shared__ u16 Os[64][72];
    const int bh = blockIdx.x, b = bh >> 4, h = bh & 15;
    const int tid = threadIdx.x, lane = tid & 63, wid = tid >> 6;
    const int fr = lane & 15, kg = lane >> 4;
    const u16* Z = zbf + (size_t)bh * 16384;
    #pragma unroll
    for (int c = 0; c < 8; ++c) {
        const int i = c * 256 + tid;
        const int d = i >> 5, k8 = (i & 31) * 8;
        uint4 v = *reinterpret_cast<const uint4*>(&Z[(size_t)d * 256 + k8]);
        if (k8 < 128) {
            const float4 s0 = *reinterpret_cast<const float4*>(&invn[bh * 128 + k8]);
            const float4 s1 = *reinterpret_cast<const float4*>(&invn[bh * 128 + k8 + 4]);
            uint4 o;
            o.x = (unsigned)f2bf(__uint_as_float(v.x << 16) * s0.x) |
                  ((unsigned)f2bf(__uint_as_float(v.x & 0xffff0000u) * s0.y) << 16);
            o.y = (unsigned)f2bf(__uint_as_float(v.y << 16) * s0.z) |
                  ((unsigned)f2bf(__uint_as_float(v.y & 0xffff0000u) * s0.w) << 16);
            o.z = (unsigned)f2bf(__uint_as_float(v.z << 16) * s1.x) |
                  ((unsigned)f2bf(__uint_as_float(v.z & 0xffff0000u) * s1.y) << 16);
            o.w = (unsigned)f2bf(__uint_as_float(v.w << 16) * s1.z) |
                  ((unsigned)f2bf(__uint_as_float(v.w & 0xffff0000u) * s1.w) << 16);
            v = o;
        }
        *reinterpret_cast<uint4*>(&Zs[d][k8]) = v;
    }
    for (int nc = 0; nc < 9; ++nc) {
        const int n0 = nc * 64;
        __syncthreads();
        #pragma unroll
        for (int c = 0; c < 8; ++c) {
            const int i = c * 256 + tid;
            const int p = i >> 3, j8 = (i & 7) * 8;
            const u16* src = (p < 128) ? &phiT[((size_t)bh * 128 + p) * 576 + n0 + j8]
                                       : &kerT[((size_t)h * 128 + (p - 128)) * 576 + n0 + j8];
            uint4 v = *reinterpret_cast<const uint4*>(src);
            Qt[j8 + 0][p] = (u16)(v.x & 0xffffu); Qt[j8 + 1][p] = (u16)(v.x >> 16);
            Qt[j8 + 2][p] = (u16)(v.y & 0xffffu); Qt[j8 + 3][p] = (u16)(v.y >> 16);
            Qt[j8 + 4][p] = (u16)(v.z & 0xffffu); Qt[j8 + 5][p] = (u16)(v.z >> 16);
            Qt[j8 + 6][p] = (u16)(v.w & 0xffffu); Qt[j8 + 7][p] = (u16)(v.w >> 16);
        }
        __syncthreads();
        f32x4 acc[4];
        #pragma unroll
        for (int j = 0; j < 4; ++j) acc[j] = (f32x4){0.f, 0.f, 0.f, 0.f};
        #pragma unroll
        for (int ks = 0; ks < 8; ++ks) {
            bf16x8 aq = *reinterpret_cast<const bf16x8*>(&Qt[wid * 16 + fr][ks * 32 + kg * 8]);
            #pragma unroll
            for (int j = 0; j < 4; ++j) {
                bf16x8 bz = *reinterpret_cast<const bf16x8*>(&Zs[j * 16 + fr][ks * 32 + kg * 8]);
                acc[j] = __builtin_amdgcn_mfma_f32_16x16x32_bf16(aq, bz, acc[j], 0, 0, 0);
            }
        }
        __syncthreads();
        #pragma unroll
        for (int j = 0; j < 4; ++j)
            #pragma unroll
            for (int r = 0; r < 4; ++r)
                Os[wid * 16 + kg * 4 + r][j * 16 + fr] = f2bf(acc[j][r]);
        __syncthreads();
        #pragma unroll
        for (int c = 0; c < 2; ++c) {
            const int i = c * 256 + tid;
            const int nn = i >> 3, k8 = (i & 7) * 8;
            *reinterpret_cast<uint4*>(&outp[((size_t)b * NN + n0 + nn) * 1024 + h * 64 + k8]) =
                *reinterpret_cast<const uint4*>(&Os[nn][k8]);
        }
    }
}

// ---------- K12: proj (128x128, BK=64) ----------
__global__ __launch_bounds__(256, 4) void k_proj_mfma(const u16* __restrict__ A,
                                                      const u16* __restrict__ B,
                                                      const float* __restrict__ bias,
                                                      float* __restrict__ out) {
    __shared__ u16 As[128][64];
    __shared__ u16 Bs[128][64];
    const int tid = threadIdx.x;
    const int wid = tid >> 6, lane = tid & 63;
    const int wr = (wid >> 1) * 64, wc = (wid & 1) * 64;
    const int lb = (blockIdx.x & 7) * 144 + (blockIdx.x >> 3);
    const int bm = lb >> 3, bn = lb & 7;
    const int row0 = bm * 128, col0 = bn * 128;
    const int fr = lane & 15, kg = lane >> 4;
    f32x4 acc[4][4];
    #pragma unroll
    for (int i = 0; i < 4; ++i)
        #pragma unroll
        for (int j = 0; j < 4; ++j) acc[i][j] = (f32x4){0.f, 0.f, 0.f, 0.f};
    nt128_k64(A + (size_t)row0 * 1024, B + (size_t)col0 * 1024, 1024, As, Bs, acc);
    #pragma unroll
    for (int i = 0; i < 4; ++i)
        #pragma unroll
        for (int r = 0; r < 4; ++r) {
            const int grow = row0 + wr + i * 16 + kg * 4 + r;
            #pragma unroll
            for (int j = 0; j < 4; ++j) {
                const int gcol = col0 + wc + j * 16 + fr;
                out[(size_t)grow * 1024 + gcol] = acc[i][j][r] + bias[gcol];
            }
        }
}

// ---------- launch ----------
extern "C" void kernel_launch(void* const* d_in, const int* in_sizes, int n_in,
                              void* d_out, int out_size, void* d_ws, size_t ws_size,
                              hipStream_t stream) {
    const float* x      = (const float*)d_in[0];
    const float* qkv_w  = (const float*)d_in[1];
    const float* proj_w = (const float*)d_in[2];
    const float* proj_b = (const float*)d_in[3];
    const float* rand_m = (const float*)d_in[4];
    const float* kern   = (const float*)d_in[5];
    const float* Lk     = (const float*)d_in[6];
    const float* llam   = (const float*)d_in[7];
    const float* lL     = (const float*)d_in[8];
    float* out = (float*)d_out;

    const size_t NEED = 248514560ull;
    if (ws_size < NEED) { hipMemsetAsync(d_out, 0, (size_t)out_size * 4, stream); return; }
    char* base = (char*)d_ws;
    u16*   pwb  = (u16*)  (base + 0);
    float* effL = (float*)(base + 2097152);
    u16*   Lkb  = (u16*)  (base + 2099200);
    u16*   LkTb = (u16*)  (base + 2230272);
    u16*   kerT = (u16*)  (base + 2361344);
    u16*   randT= (u16*)  (base + 4720640);
    u16*   phiT = (u16*)  (base + 4982784);
    u16*   kkb  = (u16*)  (base + 80480256);
    float* inpT = (float*)(base + 147589120);
    u16*   zbf  = (u16*)  (base + 181143552);
    float* invn = (float*)(base + 248252416);
    u16*   vT   = (u16*)  (base + 80480256);
    u16*   wb   = (u16*)  (base + 118228992);
    u16*   qbf  = (u16*)  (base + 147589120);
    u16*   xb   = (u16*)  (base + 197920768);
    u16*   outp = (u16*)  (base + 80480256);

    k_prep       <<<22352, 256, 0, stream>>>(x, qkv_w, proj_w, Lk, rand_m, kern,
                                             xb, wb, pwb, Lkb, LkTb, randT, kerT);
    k_qkv_mfma   <<<2304,  256, 0, stream>>>(xb, wb, qbf, vT);
    k_phi_mfma   <<<512,   256, 0, stream>>>(qbf, randT, phiT, invn);
    k_inp_mfma   <<<512,   256, 0, stream>>>(vT, phiT, kerT, invn, inpT);
    k_gram_fat   <<<512,   512, 0, stream>>>(phiT, kerT, invn, lL, kkb, effL);
    k_lk_fused   <<<512,   512, 0, stream>>>(Lkb, LkTb, kkb);
    k_ista_reg   <<<1024,  256, 0, stream>>>(kkb, inpT, zbf, effL, llam);
    k_outpre_mfma<<<512,   256, 0, stream>>>(phiT, kerT, zbf, invn, outp);
    k_proj_mfma  <<<1152,  256, 0, stream>>>(outp, pwb, proj_b, out);
}

// Round 23
// 559.988 us; speedup vs baseline: 1.1715x; 1.1715x over previous
//
#include <hip/hip_runtime.h>
#include <math.h>

#define NN 576
#define LAMC 0.1f
#define NUM_STEP 10

typedef unsigned short u16;
typedef __attribute__((ext_vector_type(8))) short bf16x8;
typedef __attribute__((ext_vector_type(4))) float f32x4;

__device__ __forceinline__ float bf2f(u16 u) { return __uint_as_float(((unsigned)u) << 16); }
__device__ __forceinline__ u16 f2bf(float f) {
    unsigned x = __float_as_uint(f);
    return (u16)((x + 0x7fffu + ((x >> 16) & 1u)) >> 16);
}
__device__ __forceinline__ float soft_thresh(float z, float t) {
    float a = fabsf(z) - t;
    float g = 0.5f * a * (1.0f + erff(a * 0.70710678118654752f));
    float s = (z > 0.0f) ? 1.0f : ((z < 0.0f) ? -1.0f : 0.0f);
    return s * g;
}
// async global->LDS, 16B per lane: lds dest = uniform base + lane*16
__device__ __forceinline__ void gload16(const u16* g, const u16* l) {
    __builtin_amdgcn_global_load_lds(
        (const __attribute__((address_space(1))) unsigned int*)(g),
        (__attribute__((address_space(3))) unsigned int*)(l), 16, 0, 0);
}

// ---------- K0: merged preps ----------
__global__ __launch_bounds__(256) void k_prep(const float* __restrict__ x,
                                              const float* __restrict__ qkv_w,
                                              const float* __restrict__ proj_w,
                                              const float* __restrict__ Lk,
                                              const float* __restrict__ rand_m,
                                              const float* __restrict__ kern,
                                              u16* __restrict__ xb,
                                              u16* __restrict__ wb,
                                              u16* __restrict__ pwb,
                                              u16* __restrict__ Lkb,
                                              u16* __restrict__ LkTb,
                                              u16* __restrict__ randT,
                                              u16* __restrict__ kerT) {
    const int b = blockIdx.x;
    if (b < 18432) {
        const int i = b * 256 + threadIdx.x;
        float4 v = reinterpret_cast<const float4*>(x)[i];
        ushort4 o; o.x = f2bf(v.x); o.y = f2bf(v.y); o.z = f2bf(v.z); o.w = f2bf(v.w);
        reinterpret_cast<ushort4*>(xb)[i] = o;
    } else if (b < 20480) {
        const int i = (b - 18432) * 256 + threadIdx.x;
        float4 v = reinterpret_cast<const float4*>(qkv_w)[i];
        ushort4 o; o.x = f2bf(v.x); o.y = f2bf(v.y); o.z = f2bf(v.z); o.w = f2bf(v.w);
        reinterpret_cast<ushort4*>(wb)[i] = o;
    } else if (b < 21504) {
        const int i = (b - 20480) * 256 + threadIdx.x;
        float4 v = reinterpret_cast<const float4*>(proj_w)[i];
        ushort4 o; o.x = f2bf(v.x); o.y = f2bf(v.y); o.z = f2bf(v.z); o.w = f2bf(v.w);
        reinterpret_cast<ushort4*>(pwb)[i] = o;
    } else if (b < 21568) {
        const int i = (b - 21504) * 256 + threadIdx.x;
        float4 v = reinterpret_cast<const float4*>(Lk)[i];
        ushort4 o; o.x = f2bf(v.x); o.y = f2bf(v.y); o.z = f2bf(v.z); o.w = f2bf(v.w);
        reinterpret_cast<ushort4*>(Lkb)[i] = o;
    } else if (b < 21824) {
        const int r = b - 21568, s = threadIdx.x;
        LkTb[r * 256 + s] = f2bf(Lk[s * 256 + r]);
    } else if (b < 22336) {
        const int i = (b - 21824) * 256 + threadIdx.x;
        const int h = i >> 13, rem = i & 8191;
        const int m = rem >> 6, d = rem & 63;
        randT[i] = f2bf(rand_m[(size_t)h * 8192 + d * 128 + m]);
    } else {
        const int h = b - 22336, m = threadIdx.x;
        if (m < 128) {
            const float* kp = kern + (size_t)h * NN * 128 + m;
            float s = 0.f;
            for (int n = 0; n < NN; ++n) { float v = kp[(size_t)n * 128]; s = fmaf(v, v, s); }
            const float inv = 1.0f / fmaxf(sqrtf(s), 1e-12f);
            u16* op = kerT + ((size_t)h * 128 + m) * 576;
            for (int n = 0; n < NN; ++n) op[n] = f2bf(kp[(size_t)n * 128] * inv);
        }
    }
}

// ---------- shared NT-MFMA 128x128 core, BK=64, slot-swizzled ----------
__device__ __forceinline__ void nt128_k64(const u16* __restrict__ A, const u16* __restrict__ B,
                                          const int K, u16 (&As)[128][64], u16 (&Bs)[128][64],
                                          f32x4 (&acc)[4][4]) {
    const int tid = threadIdx.x;
    const int lane = tid & 63, wid = tid >> 6;
    const int wr = (wid >> 1) * 64, wc = (wid & 1) * 64;
    const int fr = lane & 15, kg = lane >> 4;
    const int lrow = lane >> 3;
    const int lslot = (lane & 7) ^ ((lane >> 3) & 7);
    for (int k0 = 0; k0 < K; k0 += 64) {
        __syncthreads();
        #pragma unroll
        for (int c = 0; c < 4; ++c) {
            const int ch = wid + c * 4;
            gload16(&A[(size_t)(ch * 8 + lrow) * K + k0 + lslot * 8], &As[ch * 8][0]);
            gload16(&B[(size_t)(ch * 8 + lrow) * K + k0 + lslot * 8], &Bs[ch * 8][0]);
        }
        __syncthreads();
        #pragma unroll
        for (int ks = 0; ks < 2; ++ks) {
            const int rs = ((ks * 4 + kg) ^ (fr & 7)) * 8;
            bf16x8 af[4], bfr[4];
            #pragma unroll
            for (int i = 0; i < 4; ++i) af[i] = *reinterpret_cast<const bf16x8*>(&As[wr + i * 16 + fr][rs]);
            #pragma unroll
            for (int j = 0; j < 4; ++j) bfr[j] = *reinterpret_cast<const bf16x8*>(&Bs[wc + j * 16 + fr][rs]);
            #pragma unroll
            for (int i = 0; i < 4; ++i)
                #pragma unroll
                for (int j = 0; j < 4; ++j)
                    acc[i][j] = __builtin_amdgcn_mfma_f32_16x16x32_bf16(af[i], bfr[j], acc[i][j], 0, 0, 0);
        }
    }
}

// ---------- K1: qkv GEMM (128x128, BK=64) -> qbf / vT ----------
__global__ __launch_bounds__(256) void k_qkv_mfma(const u16* __restrict__ A,
                                                  const u16* __restrict__ B,
                                                  u16* __restrict__ qbf,
                                                  u16* __restrict__ vT) {
    __shared__ u16 As[128][64];
    __shared__ u16 Bs[128][64];
    const int tid = threadIdx.x;
    const int wid = tid >> 6, lane = tid & 63;
    const int wr = (wid >> 1) * 64, wc = (wid & 1) * 64;
    const int lb = (blockIdx.x & 7) * 288 + (blockIdx.x >> 3);
    const int bm = lb >> 4, bn = lb & 15;
    const int row0 = bm * 128, col0 = bn * 128;
    const int fr = lane & 15, kg = lane >> 4;
    f32x4 acc[4][4];
    #pragma unroll
    for (int i = 0; i < 4; ++i)
        #pragma unroll
        for (int j = 0; j < 4; ++j) acc[i][j] = (f32x4){0.f, 0.f, 0.f, 0.f};
    nt128_k64(A + (size_t)row0 * 1024, B + (size_t)col0 * 1024, 1024, As, Bs, acc);
    const bool isQ = (col0 < 1024);
    if (isQ) {
        const float qscale = 0.35355339059327373f;
        #pragma unroll
        for (int i = 0; i < 4; ++i) {
            #pragma unroll
            for (int r = 0; r < 4; ++r) {
                const int grow = row0 + wr + i * 16 + kg * 4 + r;
                const int b = grow / NN, n = grow % NN;
                #pragma unroll
                for (int j = 0; j < 4; ++j) {
                    const int gcol = col0 + wc + j * 16 + fr;
                    const int h = gcol >> 6, d = gcol & 63;
                    qbf[(((size_t)b * 16 + h) * NN + n) * 64 + d] = f2bf(acc[i][j][r] * qscale);
                }
            }
        }
    } else {
        #pragma unroll
        for (int i = 0; i < 4; ++i) {
            const int gb = row0 + wr + i * 16 + kg * 4;
            const int b = gb / NN, n = gb % NN;
            #pragma unroll
            for (int j = 0; j < 4; ++j) {
                const int c2 = col0 + wc + j * 16 + fr - 1024;
                const int h = c2 >> 6, d = c2 & 63;
                ushort4 pk;
                pk.x = f2bf(acc[i][j][0]); pk.y = f2bf(acc[i][j][1]);
                pk.z = f2bf(acc[i][j][2]); pk.w = f2bf(acc[i][j][3]);
                *reinterpret_cast<ushort4*>(&vT[(((size_t)b * 16 + h) * 64 + d) * 576 + n]) = pk;
            }
        }
    }
}

// ---------- K2: performer phi via MFMA -> phiT (UNSCALED) + invn ----------
__global__ __launch_bounds__(256) void k_phi_mfma(const u16* __restrict__ qbf,
                                                  const u16* __restrict__ randT,
                                                  u16* __restrict__ phiT,
                                                  float* __restrict__ invn) {
    __shared__ u16 Rs[128][72];
    __shared__ u16 Qs[64][72];
    __shared__ u16 Ph[128][72];
    __shared__ float sn[64];
    __shared__ float snorm[256];
    const int bh = blockIdx.x, h = bh & 15;
    const int tid = threadIdx.x, lane = tid & 63, wid = tid >> 6;
    const int fr = lane & 15, kg = lane >> 4;
    #pragma unroll
    for (int c = 0; c < 4; ++c) {
        const int i = c * 256 + tid;
        const int m = i >> 3, k8 = (i & 7) * 8;
        *reinterpret_cast<uint4*>(&Rs[m][k8]) =
            *reinterpret_cast<const uint4*>(&randT[((size_t)h * 128 + m) * 64 + k8]);
    }
    const u16* Q = qbf + (size_t)bh * 576 * 64;
    const float invM = 0.08838834764831845f;
    float accs = 0.f;
    const int m2 = tid >> 1, c0 = (tid & 1) * 32;
    for (int nc = 0; nc < 9; ++nc) {
        const int n0 = nc * 64;
        __syncthreads();
        #pragma unroll
        for (int c = 0; c < 2; ++c) {
            const int i = c * 256 + tid;
            const int r = i >> 3, k8 = (i & 7) * 8;
            *reinterpret_cast<uint4*>(&Qs[r][k8]) =
                *reinterpret_cast<const uint4*>(&Q[(size_t)(n0 + r) * 64 + k8]);
        }
        __syncthreads();
        if (tid < 64) {
            float s = 0.f;
            #pragma unroll 8
            for (int d = 0; d < 64; ++d) { float v = bf2f(Qs[tid][d]); s = fmaf(v, v, s); }
            sn[tid] = 0.5f * s;
        }
        f32x4 acc[2][4];
        #pragma unroll
        for (int i = 0; i < 2; ++i)
            #pragma unroll
            for (int j = 0; j < 4; ++j) acc[i][j] = (f32x4){0.f, 0.f, 0.f, 0.f};
        #pragma unroll
        for (int ks = 0; ks < 2; ++ks) {
            bf16x8 af[2], bq[4];
            #pragma unroll
            for (int i = 0; i < 2; ++i)
                af[i] = *reinterpret_cast<const bf16x8*>(&Rs[wid * 32 + i * 16 + fr][ks * 32 + kg * 8]);
            #pragma unroll
            for (int j = 0; j < 4; ++j)
                bq[j] = *reinterpret_cast<const bf16x8*>(&Qs[j * 16 + fr][ks * 32 + kg * 8]);
            #pragma unroll
            for (int i = 0; i < 2; ++i)
                #pragma unroll
                for (int j = 0; j < 4; ++j)
                    acc[i][j] = __builtin_amdgcn_mfma_f32_16x16x32_bf16(af[i], bq[j], acc[i][j], 0, 0, 0);
        }
        __syncthreads();
        #pragma unroll
        for (int j = 0; j < 4; ++j) {
            const int n = j * 16 + fr;
            const float sv = sn[n];
            #pragma unroll
            for (int i = 0; i < 2; ++i) {
                #pragma unroll
                for (int r = 0; r < 4; ++r) {
                    const int m = wid * 32 + i * 16 + kg * 4 + r;
                    Ph[m][n] = f2bf(expf(acc[i][j][r] - sv) * invM);
                }
            }
        }
        __syncthreads();
        #pragma unroll
        for (int c = 0; c < 4; ++c) {
            const int i = c * 256 + tid;
            const int mm = i >> 3, k8 = (i & 7) * 8;
            *reinterpret_cast<uint4*>(&phiT[((size_t)bh * 128 + mm) * 576 + n0 + k8]) =
                *reinterpret_cast<const uint4*>(&Ph[mm][k8]);
        }
        {
            float s = 0.f;
            #pragma unroll 8
            for (int t = 0; t < 32; ++t) { float v = bf2f(Ph[m2][c0 + t]); s = fmaf(v, v, s); }
            accs += s;
        }
    }
    snorm[tid] = accs;
    __syncthreads();
    if (tid < 128)
        invn[bh * 128 + tid] = 1.0f / fmaxf(sqrtf(snorm[tid * 2] + snorm[tid * 2 + 1]), 1e-12f);
}

// ---------- K5: gram FAT (BK=64) + fused eff_L ----------
__global__ __launch_bounds__(512, 2) void k_gram_fat(const u16* __restrict__ phiT,
                                                     const u16* __restrict__ kerT,
                                                     const float* __restrict__ invn,
                                                     const float* __restrict__ lL,
                                                     u16* __restrict__ kkb,
                                                     float* __restrict__ effL) {
    __shared__ u16 Qs[256][64];
    __shared__ float rs2[2][256];
    __shared__ float red[256];
    const int bh = blockIdx.x, h = bh & 15;
    const int tid = threadIdx.x, lane = tid & 63, wid = tid >> 6;
    const int wr = (wid & 3) * 64, wc = (wid >> 2) * 128;
    const int fr = lane & 15, kg = lane >> 4;
    const int lrow = lane >> 3;
    const int lslot = (lane & 7) ^ ((lane >> 3) & 7);
    f32x4 acc[4][8];
    #pragma unroll
    for (int i = 0; i < 4; ++i)
        #pragma unroll
        for (int j = 0; j < 8; ++j) acc[i][j] = (f32x4){0.f, 0.f, 0.f, 0.f};
    for (int k0 = 0; k0 < 576; k0 += 64) {
        __syncthreads();
        #pragma unroll
        for (int c = 0; c < 4; ++c) {
            const int rowbase = (wid * 4 + c) * 8;
            const int p = rowbase + lrow;
            const u16* src = (p < 128)
                ? phiT + ((size_t)bh * 128 + p) * 576 + k0 + lslot * 8
                : kerT + ((size_t)h * 128 + (p - 128)) * 576 + k0 + lslot * 8;
            gload16(src, &Qs[rowbase][0]);
        }
        __syncthreads();
        #pragma unroll
        for (int ks = 0; ks < 2; ++ks) {
            const int rs = ((ks * 4 + kg) ^ (fr & 7)) * 8;
            bf16x8 af[4], bf[8];
            #pragma unroll
            for (int i = 0; i < 4; ++i) af[i] = *reinterpret_cast<const bf16x8*>(&Qs[wr + i * 16 + fr][rs]);
            #pragma unroll
            for (int j = 0; j < 8; ++j) bf[j] = *reinterpret_cast<const bf16x8*>(&Qs[wc + j * 16 + fr][rs]);
            #pragma unroll
            for (int i = 0; i < 4; ++i)
                #pragma unroll
                for (int j = 0; j < 8; ++j)
                    acc[i][j] = __builtin_amdgcn_mfma_f32_16x16x32_bf16(af[i], bf[j], acc[i][j], 0, 0, 0);
        }
    }
    const float* iv = invn + bh * 128;
    u16* C = kkb + (size_t)bh * 65536;
    float sq[8];
    #pragma unroll
    for (int j = 0; j < 8; ++j) { const int q = wc + j * 16 + fr; sq[j] = (q < 128) ? iv[q] : 1.0f; }
    #pragma unroll
    for (int i = 0; i < 4; ++i)
        #pragma unroll
        for (int rr = 0; rr < 4; ++rr) {
            const int p = wr + i * 16 + kg * 4 + rr;
            const float sp = (p < 128) ? iv[p] : 1.0f;
            float rsum = 0.f;
            #pragma unroll
            for (int j = 0; j < 8; ++j) {
                const float val = acc[i][j][rr] * sp * sq[j];
                C[(size_t)p * 256 + wc + j * 16 + fr] = f2bf(val);
                rsum += fabsf(val);
            }
            #pragma unroll
            for (int mk = 1; mk < 16; mk <<= 1) rsum += __shfl_xor(rsum, mk);
            if (fr == 0) rs2[wid >> 2][p] = rsum;
        }
    __syncthreads();
    if (tid < 256) red[tid] = rs2[0][tid] + rs2[1][tid];
    __syncthreads();
    for (int st = 128; st > 0; st >>= 1) {
        if (tid < st) red[tid] = fmaxf(red[tid], red[tid + st]);
        __syncthreads();
    }
    if (tid == 0) effL[bh] = (red[0] + 1.0f) / lL[0];
}

// ---------- K6: fused Lk sandwich: kk = Lk·kk·Lk in ONE kernel (t in LDS) ----------
__global__ __launch_bounds__(512, 1) void k_lk_fused(const u16* __restrict__ Lkb,
                                                     const u16* __restrict__ LkTb,
                                                     u16* __restrict__ kkb) {
    __shared__ u16 smem[73728];                                    // 147456 B
    u16 (*t)[256]  = reinterpret_cast<u16(*)[256]>(smem);
    u16 (*As1)[64] = reinterpret_cast<u16(*)[64]>(smem);
    u16 (*Bs1)[64] = reinterpret_cast<u16(*)[64]>(smem + 16384);
    u16 (*Bs2)[32] = reinterpret_cast<u16(*)[32]>(smem + 65536);
    const int bh = blockIdx.x;
    const int tid = threadIdx.x, lane = tid & 63, wid = tid >> 6;
    const int wr = (wid & 3) * 64, wc = (wid >> 2) * 128;
    const int fr = lane & 15, kg = lane >> 4;
    const u16* B1 = kkb + (size_t)bh * 65536;
    f32x4 acc[4][8];
    #pragma unroll
    for (int i = 0; i < 4; ++i)
        #pragma unroll
        for (int j = 0; j < 8; ++j) acc[i][j] = (f32x4){0.f, 0.f, 0.f, 0.f};
    {
        const int lrow = lane >> 3;
        const int lslot = (lane & 7) ^ ((lane >> 3) & 7);
        for (int k0 = 0; k0 < 256; k0 += 64) {
            __syncthreads();
            #pragma unroll
            for (int c = 0; c < 4; ++c) {
                const int rowbase = (wid * 4 + c) * 8;
                const int p = rowbase + lrow;
                gload16(&Lkb[(size_t)p * 256 + k0 + lslot * 8], &As1[rowbase][0]);
                gload16(&B1[(size_t)p * 256 + k0 + lslot * 8], &Bs1[rowbase][0]);
            }
            __syncthreads();
            #pragma unroll
            for (int ks = 0; ks < 2; ++ks) {
                const int rs = ((ks * 4 + kg) ^ (fr & 7)) * 8;
                bf16x8 af[4], bf[8];
                #pragma unroll
                for (int i = 0; i < 4; ++i) af[i] = *reinterpret_cast<const bf16x8*>(&As1[wr + i * 16 + fr][rs]);
                #pragma unroll
                for (int j = 0; j < 8; ++j) bf[j] = *reinterpret_cast<const bf16x8*>(&Bs1[wc + j * 16 + fr][rs]);
                #pragma unroll
                for (int i = 0; i < 4; ++i)
                    #pragma unroll
                    for (int j = 0; j < 8; ++j)
                        acc[i][j] = __builtin_amdgcn_mfma_f32_16x16x32_bf16(af[i], bf[j], acc[i][j], 0, 0, 0);
            }
        }
    }
    __syncthreads();
    #pragma unroll
    for (int i = 0; i < 4; ++i)
        #pragma unroll
        for (int rr = 0; rr < 4; ++rr) {
            const int p = wr + i * 16 + kg * 4 + rr;
            #pragma unroll
            for (int j = 0; j < 8; ++j) {
                const int q = wc + j * 16 + fr;
                t[p][q ^ ((p & 7) << 3)] = f2bf(acc[i][j][rr]);
            }
        }
    __syncthreads();
    #pragma unroll
    for (int i = 0; i < 4; ++i)
        #pragma unroll
        for (int j = 0; j < 8; ++j) acc[i][j] = (f32x4){0.f, 0.f, 0.f, 0.f};
    {
        const int lrow2 = lane >> 2;
        const int lslot2 = (lane & 3) ^ ((lane >> 3) & 3);
        const int rslot2 = (kg ^ ((fr >> 1) & 3)) * 8;
        for (int k0 = 0; k0 < 256; k0 += 32) {
            __syncthreads();
            #pragma unroll
            for (int c = 0; c < 2; ++c) {
                const int chunk = wid * 2 + c;
                const int p = chunk * 16 + lrow2;
                gload16(&LkTb[(size_t)p * 256 + k0 + lslot2 * 8], &Bs2[chunk * 16][0]);
            }
            __syncthreads();
            bf16x8 af[4], bf[8];
            #pragma unroll
            for (int i = 0; i < 4; ++i) {
                const int p = wr + i * 16 + fr;
                af[i] = *reinterpret_cast<const bf16x8*>(&t[p][(k0 + kg * 8) ^ ((p & 7) << 3)]);
            }
            #pragma unroll
            for (int j = 0; j < 8; ++j) bf[j] = *reinterpret_cast<const bf16x8*>(&Bs2[wc + j * 16 + fr][rslot2]);
            #pragma unroll
            for (int i = 0; i < 4; ++i)
                #pragma unroll
                for (int j = 0; j < 8; ++j)
                    acc[i][j] = __builtin_amdgcn_mfma_f32_16x16x32_bf16(af[i], bf[j], acc[i][j], 0, 0, 0);
        }
    }
    u16* C = kkb + (size_t)bh * 65536;
    #pragma unroll
    for (int i = 0; i < 4; ++i)
        #pragma unroll
        for (int rr = 0; rr < 4; ++rr) {
            const int p = wr + i * 16 + kg * 4 + rr;
            #pragma unroll
            for (int j = 0; j < 8; ++j)
                C[(size_t)p * 256 + wc + j * 16 + fr] = f2bf(acc[i][j][rr]);
        }
}

// ---------- K7: inp (MFMA, BK=64, async-staged, invn folded at store) ----------
__global__ __launch_bounds__(256) void k_inp_mfma(const u16* __restrict__ vT,
                                                  const u16* __restrict__ phiT,
                                                  const u16* __restrict__ kerT,
                                                  const float* __restrict__ invn,
                                                  float* __restrict__ inpT) {
    __shared__ u16 As[64][64];
    __shared__ u16 Bs[256][64];
    const int bh = blockIdx.x, h = bh & 15;
    const int tid = threadIdx.x, lane = tid & 63, wid = tid >> 6;
    const int fr = lane & 15, kg = lane >> 4;
    const int lrow = lane >> 3;
    const int lslot = (lane & 7) ^ ((lane >> 3) & 7);
    const u16* Av = vT + (size_t)bh * 64 * 576;
    f32x4 acc[4][4];
    #pragma unroll
    for (int i = 0; i < 4; ++i)
        #pragma unroll
        for (int j = 0; j < 4; ++j) acc[i][j] = (f32x4){0.f, 0.f, 0.f, 0.f};
    for (int k0 = 0; k0 < 576; k0 += 64) {
        __syncthreads();
        #pragma unroll
        for (int c = 0; c < 2; ++c) {
            const int chunk = wid * 2 + c;
            gload16(&Av[(size_t)(chunk * 8 + lrow) * 576 + k0 + lslot * 8], &As[chunk * 8][0]);
        }
        #pragma unroll
        for (int c = 0; c < 8; ++c) {
            const int chunk = wid + c * 4;
            const int p = chunk * 8 + lrow;
            const u16* src = (p < 128)
                ? phiT + ((size_t)bh * 128 + p) * 576 + k0 + lslot * 8
                : kerT + ((size_t)h * 128 + (p - 128)) * 576 + k0 + lslot * 8;
            gload16(src, &Bs[chunk * 8][0]);
        }
        __syncthreads();
        #pragma unroll
        for (int ks = 0; ks < 2; ++ks) {
            const int rs = ((ks * 4 + kg) ^ (fr & 7)) * 8;
            bf16x8 af[4], bfr[4];
            #pragma unroll
            for (int i = 0; i < 4; ++i) af[i] = *reinterpret_cast<const bf16x8*>(&As[i * 16 + fr][rs]);
            #pragma unroll
            for (int j = 0; j < 4; ++j) bfr[j] = *reinterpret_cast<const bf16x8*>(&Bs[wid * 64 + j * 16 + fr][rs]);
            #pragma unroll
            for (int i = 0; i < 4; ++i)
                #pragma unroll
                for (int j = 0; j < 4; ++j)
                    acc[i][j] = __builtin_amdgcn_mfma_f32_16x16x32_bf16(af[i], bfr[j], acc[i][j], 0, 0, 0);
        }
    }
    float* O = inpT + (size_t)bh * 16384;
    float sc[4];
    #pragma unroll
    for (int j = 0; j < 4; ++j) {
        const int p = wid * 64 + j * 16 + fr;
        sc[j] = (p < 128) ? invn[bh * 128 + p] : 1.0f;
    }
    #pragma unroll
    for (int i = 0; i < 4; ++i)
        #pragma unroll
        for (int r = 0; r < 4; ++r)
            #pragma unroll
            for (int j = 0; j < 4; ++j)
                O[(size_t)(i * 16 + kg * 4 + r) * 256 + wid * 64 + j * 16 + fr] = acc[i][j][r] * sc[j];
}

// ---------- K10: fused ISTA, double-buffered z (1 barrier/step), XCD-paired ----------
__global__ __launch_bounds__(256) void k_ista_reg(const u16* __restrict__ kkl,
                                                  const float* __restrict__ inpT,
                                                  u16* __restrict__ zbf,
                                                  const float* __restrict__ effL,
                                                  const float* __restrict__ llam) {
    __shared__ u16 zs[2][32][256];
    const int lb = (blockIdx.x & 7) * 128 + (blockIdx.x >> 3);
    const int bh = lb >> 1, dh = lb & 1;
    const int tid = threadIdx.x, lane = tid & 63, wid = tid >> 6;
    const int wr = wid * 64;
    const int fr = lane & 15, kg = lane >> 4;
    const u16* Kk = kkl + (size_t)bh * 65536;
    bf16x8 af[4][8];
    #pragma unroll
    for (int i = 0; i < 4; ++i) {
        const int p = wr + i * 16 + fr;
        #pragma unroll
        for (int c = 0; c < 8; ++c)
            af[i][c] = *reinterpret_cast<const bf16x8*>(&Kk[(size_t)p * 256 + c * 32 + kg * 8]);
    }
    const float* I = inpT + (size_t)bh * 16384 + (size_t)dh * 32 * 256;
    const float invL = 1.0f / effL[bh];
    const float lam = llam[0] * LAMC;
    const float thr = lam * invL;
    float4 ip[4][2];
    #pragma unroll
    for (int i = 0; i < 4; ++i) {
        const int pb = wr + i * 16 + kg * 4;
        #pragma unroll
        for (int j = 0; j < 2; ++j) {
            const int d = j * 16 + fr;
            ip[i][j] = *reinterpret_cast<const float4*>(&I[(size_t)d * 256 + pb]);
            const int pc = pb ^ ((d & 7) << 3);
            ushort4 pk;
            pk.x = f2bf(soft_thresh(ip[i][j].x, lam));
            pk.y = f2bf(soft_thresh(ip[i][j].y, lam));
            pk.z = f2bf(soft_thresh(ip[i][j].z, lam));
            pk.w = f2bf(soft_thresh(ip[i][j].w, lam));
            *reinterpret_cast<ushort4*>(&zs[0][d][pc]) = pk;
        }
    }
    __syncthreads();
    int cur = 0;
    for (int step = 0; step < NUM_STEP; ++step) {
        f32x4 acc[4][2];
        #pragma unroll
        for (int i = 0; i < 4; ++i)
            #pragma unroll
            for (int j = 0; j < 2; ++j) acc[i][j] = (f32x4){0.f, 0.f, 0.f, 0.f};
        #pragma unroll
        for (int c = 0; c < 8; ++c) {
            bf16x8 bz[2];
            #pragma unroll
            for (int j = 0; j < 2; ++j) {
                const int d = j * 16 + fr;
                bz[j] = *reinterpret_cast<const bf16x8*>(&zs[cur][d][(c * 32 + kg * 8) ^ ((d & 7) << 3)]);
            }
            #pragma unroll
            for (int i = 0; i < 4; ++i)
                #pragma unroll
                for (int j = 0; j < 2; ++j)
                    acc[i][j] = __builtin_amdgcn_mfma_f32_16x16x32_bf16(af[i][c], bz[j], acc[i][j], 0, 0, 0);
        }
        #pragma unroll
        for (int i = 0; i < 4; ++i) {
            const int pb = wr + i * 16 + kg * 4;
            #pragma unroll
            for (int j = 0; j < 2; ++j) {
                const int d = j * 16 + fr;
                const int pc = pb ^ ((d & 7) << 3);
                ushort4 zo = *reinterpret_cast<const ushort4*>(&zs[cur][d][pc]);
                ushort4 pk;
                pk.x = f2bf(soft_thresh(bf2f(zo.x) - (acc[i][j][0] - ip[i][j].x) * invL, thr));
                pk.y = f2bf(soft_thresh(bf2f(zo.y) - (acc[i][j][1] - ip[i][j].y) * invL, thr));
                pk.z = f2bf(soft_thresh(bf2f(zo.z) - (acc[i][j][2] - ip[i][j].z) * invL, thr));
                pk.w = f2bf(soft_thresh(bf2f(zo.w) - (acc[i][j][3] - ip[i][j].w) * invL, thr));
                *reinterpret_cast<ushort4*>(&zs[cur ^ 1][d][pc]) = pk;
            }
        }
        __syncthreads();
        cur ^= 1;
    }
    u16* Z = zbf + (size_t)bh * 16384 + (size_t)dh * 32 * 256;
    #pragma unroll
    for (int c = 0; c < 4; ++c) {
        const int i = c * 256 + tid;
        const int d = i >> 5, p8 = (i & 31) * 8;
        *reinterpret_cast<uint4*>(&Z[(size_t)d * 256 + p8]) =
            *reinterpret_cast<const uint4*>(&zs[0][d][p8 ^ ((d & 7) << 3)]);
    }
}

// ---------- K11: out_pre via MFMA (invn folded into Zs staging) ----------
__global__ __launch_bounds__(256) void k_outpre_mfma(const u16* __restrict__ phiT,
                                                     const u16* __restrict__ kerT,
                                                     const u16* __restrict__ zbf,
                                                     const float* __restrict__ invn,
                                                     u16* __restrict__ outp) {
    __shared__ u16 Zs[64][264];
    __shared__ u16 Qt[64][264];
    __shared__ u16 Os[64][72];
    const int bh = blockIdx.x, b = bh >> 4, h = bh & 15;
    const int tid = threadIdx.x, lane = tid & 63, wid = tid >> 6;
    const int fr = lane & 15, kg = lane >> 4;
    const u16* Z = zbf + (size_t)bh * 16384;
    #pragma unroll
    for (int c = 0; c < 8; ++c) {
        const int i = c * 256 + tid;
        const int d = i >> 5, k8 = (i & 31) * 8;
        uint4 v = *reinterpret_cast<const uint4*>(&Z[(size_t)d * 256 + k8]);
        if (k8 < 128) {
            const float4 s0 = *reinterpret_cast<const float4*>(&invn[bh * 128 + k8]);
            const float4 s1 = *reinterpret_cast<const float4*>(&invn[bh * 128 + k8 + 4]);
            uint4 o;
            o.x = (unsigned)f2bf(__uint_as_float(v.x << 16) * s0.x) |
                  ((unsigned)f2bf(__uint_as_float(v.x & 0xffff0000u) * s0.y) << 16);
            o.y = (unsigned)f2bf(__uint_as_float(v.y << 16) * s0.z) |
                  ((unsigned)f2bf(__uint_as_float(v.y & 0xffff0000u) * s0.w) << 16);
            o.z = (unsigned)f2bf(__uint_as_float(v.z << 16) * s1.x) |
                  ((unsigned)f2bf(__uint_as_float(v.z & 0xffff0000u) * s1.y) << 16);
            o.w = (unsigned)f2bf(__uint_as_float(v.w << 16) * s1.z) |
                  ((unsigned)f2bf(__uint_as_float(v.w & 0xffff0000u) * s1.w) << 16);
            v = o;
        }
        *reinterpret_cast<uint4*>(&Zs[d][k8]) = v;
    }
    for (int nc = 0; nc < 9; ++nc) {
        const int n0 = nc * 64;
        __syncthreads();
        #pragma unroll
        for (int c = 0; c < 8; ++c) {
            const int i = c * 256 + tid;
            const int p = i >> 3, j8 = (i & 7) * 8;
            const u16* src = (p < 128) ? &phiT[((size_t)bh * 128 + p) * 576 + n0 + j8]
                                       : &kerT[((size_t)h * 128 + (p - 128)) * 576 + n0 + j8];
            uint4 v = *reinterpret_cast<const uint4*>(src);
            Qt[j8 + 0][p] = (u16)(v.x & 0xffffu); Qt[j8 + 1][p] = (u16)(v.x >> 16);
            Qt[j8 + 2][p] = (u16)(v.y & 0xffffu); Qt[j8 + 3][p] = (u16)(v.y >> 16);
            Qt[j8 + 4][p] = (u16)(v.z & 0xffffu); Qt[j8 + 5][p] = (u16)(v.z >> 16);
            Qt[j8 + 6][p] = (u16)(v.w & 0xffffu); Qt[j8 + 7][p] = (u16)(v.w >> 16);
        }
        __syncthreads();
        f32x4 acc[4];
        #pragma unroll
        for (int j = 0; j < 4; ++j) acc[j] = (f32x4){0.f, 0.f, 0.f, 0.f};
        #pragma unroll
        for (int ks = 0; ks < 8; ++ks) {
            bf16x8 aq = *reinterpret_cast<const bf16x8*>(&Qt[wid * 16 + fr][ks * 32 + kg * 8]);
            #pragma unroll
            for (int j = 0; j < 4; ++j) {
                bf16x8 bz = *reinterpret_cast<const bf16x8*>(&Zs[j * 16 + fr][ks * 32 + kg * 8]);
                acc[j] = __builtin_amdgcn_mfma_f32_16x16x32_bf16(aq, bz, acc[j], 0, 0, 0);
            }
        }
        __syncthreads();
        #pragma unroll
        for (int j = 0; j < 4; ++j)
            #pragma unroll
            for (int r = 0; r < 4; ++r)
                Os[wid * 16 + kg * 4 + r][j * 16 + fr] = f2bf(acc[j][r]);
        __syncthreads();
        #pragma unroll
        for (int c = 0; c < 2; ++c) {
            const int i = c * 256 + tid;
            const int nn = i >> 3, k8 = (i & 7) * 8;
            *reinterpret_cast<uint4*>(&outp[((size_t)b * NN + n0 + nn) * 1024 + h * 64 + k8]) =
                *reinterpret_cast<const uint4*>(&Os[nn][k8]);
        }
    }
}

// ---------- K12: proj (128x128, BK=64) ----------
__global__ __launch_bounds__(256) void k_proj_mfma(const u16* __restrict__ A,
                                                   const u16* __restrict__ B,
                                                   const float* __restrict__ bias,
                                                   float* __restrict__ out) {
    __shared__ u16 As[128][64];
    __shared__ u16 Bs[128][64];
    const int tid = threadIdx.x;
    const int wid = tid >> 6, lane = tid & 63;
    const int wr = (wid >> 1) * 64, wc = (wid & 1) * 64;
    const int lb = (blockIdx.x & 7) * 144 + (blockIdx.x >> 3);
    const int bm = lb >> 3, bn = lb & 7;
    const int row0 = bm * 128, col0 = bn * 128;
    const int fr = lane & 15, kg = lane >> 4;
    f32x4 acc[4][4];
    #pragma unroll
    for (int i = 0; i < 4; ++i)
        #pragma unroll
        for (int j = 0; j < 4; ++j) acc[i][j] = (f32x4){0.f, 0.f, 0.f, 0.f};
    nt128_k64(A + (size_t)row0 * 1024, B + (size_t)col0 * 1024, 1024, As, Bs, acc);
    #pragma unroll
    for (int i = 0; i < 4; ++i)
        #pragma unroll
        for (int r = 0; r < 4; ++r) {
            const int grow = row0 + wr + i * 16 + kg * 4 + r;
            #pragma unroll
            for (int j = 0; j < 4; ++j) {
                const int gcol = col0 + wc + j * 16 + fr;
                out[(size_t)grow * 1024 + gcol] = acc[i][j][r] + bias[gcol];
            }
        }
}

// ---------- launch ----------
extern "C" void kernel_launch(void* const* d_in, const int* in_sizes, int n_in,
                              void* d_out, int out_size, void* d_ws, size_t ws_size,
                              hipStream_t stream) {
    const float* x      = (const float*)d_in[0];
    const float* qkv_w  = (const float*)d_in[1];
    const float* proj_w = (const float*)d_in[2];
    const float* proj_b = (const float*)d_in[3];
    const float* rand_m = (const float*)d_in[4];
    const float* kern   = (const float*)d_in[5];
    const float* Lk     = (const float*)d_in[6];
    const float* llam   = (const float*)d_in[7];
    const float* lL     = (const float*)d_in[8];
    float* out = (float*)d_out;

    const size_t NEED = 248514560ull;
    if (ws_size < NEED) { hipMemsetAsync(d_out, 0, (size_t)out_size * 4, stream); return; }
    char* base = (char*)d_ws;
    u16*   pwb  = (u16*)  (base + 0);
    float* effL = (float*)(base + 2097152);
    u16*   Lkb  = (u16*)  (base + 2099200);
    u16*   LkTb = (u16*)  (base + 2230272);
    u16*   kerT = (u16*)  (base + 2361344);
    u16*   randT= (u16*)  (base + 4720640);
    u16*   phiT = (u16*)  (base + 4982784);
    u16*   kkb  = (u16*)  (base + 80480256);
    float* inpT = (float*)(base + 147589120);
    u16*   zbf  = (u16*)  (base + 181143552);
    float* invn = (float*)(base + 248252416);
    u16*   vT   = (u16*)  (base + 80480256);
    u16*   wb   = (u16*)  (base + 118228992);
    u16*   qbf  = (u16*)  (base + 147589120);
    u16*   xb   = (u16*)  (base + 197920768);
    u16*   outp = (u16*)  (base + 80480256);

    k_prep       <<<22352, 256, 0, stream>>>(x, qkv_w, proj_w, Lk, rand_m, kern,
                                             xb, wb, pwb, Lkb, LkTb, randT, kerT);
    k_qkv_mfma   <<<2304,  256, 0, stream>>>(xb, wb, qbf, vT);
    k_phi_mfma   <<<512,   256, 0, stream>>>(qbf, randT, phiT, invn);
    k_inp_mfma   <<<512,   256, 0, stream>>>(vT, phiT, kerT, invn, inpT);
    k_gram_fat   <<<512,   512, 0, stream>>>(phiT, kerT, invn, lL, kkb, effL);
    k_lk_fused   <<<512,   512, 0, stream>>>(Lkb, LkTb, kkb);
    k_ista_reg   <<<1024,  256, 0, stream>>>(kkb, inpT, zbf, effL, llam);
    k_outpre_mfma<<<512,   256, 0, stream>>>(phiT, kerT, zbf, invn, outp);
    k_proj_mfma  <<<1152,  256, 0, stream>>>(outp, pwb, proj_b, out);
}